// Round 8
// baseline (235.895 us; speedup 1.0000x reference)
//
#include <hip/hip_runtime.h>

#define HD   64
#define NB   4
#define PROJ 256   // HD * NB columns
#define SCAN_BLK 1024

typedef __attribute__((ext_vector_type(8))) short bf16x8;
typedef __attribute__((ext_vector_type(4))) float f32x4;
typedef __attribute__((ext_vector_type(8))) unsigned short u16x8;

__device__ __forceinline__ float bf2f(unsigned short u) {
    union { unsigned int i; float f; } c; c.i = ((unsigned int)u) << 16; return c.f;
}
__device__ __forceinline__ unsigned short f2bf(float f) {
    union { float f; unsigned int i; } c; c.f = f;
    unsigned int r = c.i + 0x7FFF + ((c.i >> 16) & 1);   // round-to-nearest-even
    return (unsigned short)(r >> 16);
}

// ---- fused: blocks [0,eblocks) histogram; block eblocks packs W fragments ----
__global__ __launch_bounds__(256) void histpack_kernel(
    const int* __restrict__ dst, int* __restrict__ cnt, int n_edges,
    const float* __restrict__ Vl, unsigned short* __restrict__ wpack, int eblocks) {
    if ((int)blockIdx.x == eblocks) {
        int t = threadIdx.x;
#pragma unroll
        for (int i = 0; i < 8; ++i) {
            int s = t + i * 256;            // 0..2047 lane-slots
            int lane = s & 63;
            int ksct = s >> 6;
            int ks = ksct & 1, ct = ksct >> 1;
            int c = ct * 16 + (lane & 15);
            int o = c >> 2, b = c & 3;
            unsigned int w[4];
#pragma unroll
            for (int j = 0; j < 4; ++j) {
                int k0 = ks * 32 + ((lane >> 4) & 3) * 8 + 2 * j;
                unsigned short lo = f2bf(Vl[((size_t)b * HD + k0) * HD + o]);
                unsigned short hi = f2bf(Vl[((size_t)b * HD + k0 + 1) * HD + o]);
                w[j] = (unsigned)lo | ((unsigned)hi << 16);
            }
            *(uint4*)(wpack + (size_t)s * 8) = make_uint4(w[0], w[1], w[2], w[3]);
        }
        return;
    }
    int e = blockIdx.x * 256 + threadIdx.x;
    if (e < n_edges) atomicAdd(&cnt[dst[e]], 1);
}

// ---- scans ----
__global__ __launch_bounds__(256) void scan_a_kernel(
    const int* __restrict__ cnt, int* __restrict__ offs,
    int* __restrict__ bsum, int n) {
    __shared__ int sd[256];
    int t = threadIdx.x;
    int base = blockIdx.x * SCAN_BLK + t * 4;
    int v[4];
#pragma unroll
    for (int j = 0; j < 4; ++j) v[j] = (base + j < n) ? cnt[base + j] : 0;
    int s = v[0] + v[1] + v[2] + v[3];
    sd[t] = s; __syncthreads();
    for (int off = 1; off < 256; off <<= 1) {
        int x = (t >= off) ? sd[t - off] : 0;
        __syncthreads();
        sd[t] += x;
        __syncthreads();
    }
    int excl = sd[t] - s;
    if (t == 255) bsum[blockIdx.x] = sd[t];
    int run = excl;
#pragma unroll
    for (int j = 0; j < 4; ++j) {
        if (base + j < n) offs[base + j] = run;
        run += v[j];
    }
}

__global__ __launch_bounds__(256) void scan_b_kernel(int* __restrict__ bsum, int nblk) {
    __shared__ int sd[256];
    int t = threadIdx.x;
    int s = (t < nblk) ? bsum[t] : 0;
    sd[t] = s; __syncthreads();
    for (int off = 1; off < 256; off <<= 1) {
        int x = (t >= off) ? sd[t - off] : 0;
        __syncthreads();
        sd[t] += x;
        __syncthreads();
    }
    if (t < nblk) bsum[t] = sd[t] - s;
}

__global__ __launch_bounds__(256) void scan_c_kernel(
    int* __restrict__ offs, int* __restrict__ cursor,
    const int* __restrict__ bsum, int n) {
    int i = blockIdx.x * 256 + threadIdx.x;
    if (i < n) {
        int v = offs[i] + bsum[i / SCAN_BLK];
        offs[i] = v;
        cursor[i] = v;
    }
}

// ---- fused: blocks [0,eblocks) scatter; blocks [eblocks, eblocks+pblocks) MFMA proj ----
#define FS_STRIDE 72
__global__ __launch_bounds__(256, 4) void scatterproj_kernel(
    // scatter args
    const int* __restrict__ src, const int* __restrict__ dst,
    const int* __restrict__ etype, const float* __restrict__ norm,
    int* __restrict__ cursor, uint2* __restrict__ rec, int n_edges, int eblocks,
    // proj args
    const float* __restrict__ f, const unsigned short* __restrict__ wpack,
    unsigned short* __restrict__ xb, int n_nodes) {
    __shared__ unsigned short fs[64 * FS_STRIDE];
    if ((int)blockIdx.x < eblocks) {
        int e = blockIdx.x * 256 + threadIdx.x;
        if (e >= n_edges) return;
        int d = dst[e];
        int pos = atomicAdd(&cursor[d], 1);
        uint2 rr;
        rr.x = (unsigned)src[e] | ((unsigned)etype[e] << 20);
        rr.y = __float_as_uint(norm[e]);
        rec[pos] = rr;
        return;
    }
    int bid = blockIdx.x - eblocks;
    int t = threadIdx.x;
    int lane = t & 63;
    int wt = t >> 6;
    int n0 = bid * 64;

#pragma unroll
    for (int i = 0; i < 4; ++i) {
        int idx = t + i * 256;
        int node = idx >> 4;
        int kg = idx & 15;
        unsigned int lo = 0, hi = 0;
        if (n0 + node < n_nodes) {
            float4 v = *(const float4*)(f + ((size_t)(n0 + node) * HD + kg * 4));
            lo = (unsigned)f2bf(v.x) | ((unsigned)f2bf(v.y) << 16);
            hi = (unsigned)f2bf(v.z) | ((unsigned)f2bf(v.w) << 16);
        }
        *(uint2*)(fs + node * FS_STRIDE + kg * 4) = make_uint2(lo, hi);
    }
    __syncthreads();

    bf16x8 bfr[2];
#pragma unroll
    for (int ks = 0; ks < 2; ++ks) {
        int off = (wt * 16 + (lane & 15)) * FS_STRIDE + ks * 32 + ((lane >> 4) & 3) * 8;
        bfr[ks] = *reinterpret_cast<const bf16x8*>(&fs[off]);
    }

    f32x4 acc[16];
#pragma unroll
    for (int ct = 0; ct < 16; ++ct) acc[ct] = (f32x4){0.f, 0.f, 0.f, 0.f};

#pragma unroll
    for (int ct = 0; ct < 16; ++ct) {
#pragma unroll
        for (int ks = 0; ks < 2; ++ks) {
            bf16x8 a = *reinterpret_cast<const bf16x8*>(
                wpack + ((size_t)(ct * 2 + ks) * 64 + lane) * 8);
            acc[ct] = __builtin_amdgcn_mfma_f32_16x16x32_bf16(a, bfr[ks], acc[ct], 0, 0, 0);
        }
    }

    int node = n0 + wt * 16 + (lane & 15);
    if (node < n_nodes) {
#pragma unroll
        for (int ct = 0; ct < 16; ++ct) {
            int c0 = ct * 16 + ((lane >> 4) & 3) * 4;
            unsigned int lo = (unsigned)f2bf(acc[ct][0]) | ((unsigned)f2bf(acc[ct][1]) << 16);
            unsigned int hi = (unsigned)f2bf(acc[ct][2]) | ((unsigned)f2bf(acc[ct][3]) << 16);
            *(uint2*)(xb + (size_t)node * PROJ + c0) = make_uint2(lo, hi);
        }
    }
}

// ---- segmented sum: one dst per 32-lane half-wave, 8-deep ILP ----
__global__ __launch_bounds__(256) void seg2_kernel(
    const uint2* __restrict__ rec, const int* __restrict__ offs,
    const unsigned short* __restrict__ xb,
    const float* __restrict__ comp_l, const float* __restrict__ bias_l,
    const float* __restrict__ f, float* __restrict__ out,
    int n_nodes, int n_edges) {
    int d = blockIdx.x * 8 + (threadIdx.x >> 5);
    if (d >= n_nodes) return;
    int l32 = threadIdx.x & 31;
    int start = offs[d];
    int end = (d + 1 < n_nodes) ? offs[d + 1] : n_edges;
    int deg = end - start;
    const uint2* r = rec + start;
    float a0 = 0.f, a1 = 0.f;
    int k = 0;
    for (; k + 7 < deg; k += 8) {
        uint2 q[8]; u16x8 v[8];
#pragma unroll
        for (int j = 0; j < 8; ++j) q[j] = r[k + j];
#pragma unroll
        for (int j = 0; j < 8; ++j)
            v[j] = ((const u16x8*)(xb + (size_t)(q[j].x & 0xFFFFF) * PROJ))[l32];
#pragma unroll
        for (int j = 0; j < 8; ++j) {
            float4 c = *(const float4*)(comp_l + ((q[j].x >> 20) & 31) * NB);
            float nn = __uint_as_float(q[j].y);
            a0 += nn * (c.x*bf2f(v[j][0]) + c.y*bf2f(v[j][1]) + c.z*bf2f(v[j][2]) + c.w*bf2f(v[j][3]));
            a1 += nn * (c.x*bf2f(v[j][4]) + c.y*bf2f(v[j][5]) + c.z*bf2f(v[j][6]) + c.w*bf2f(v[j][7]));
        }
    }
    if (k + 3 < deg) {
        uint2 q[4]; u16x8 v[4];
#pragma unroll
        for (int j = 0; j < 4; ++j) q[j] = r[k + j];
#pragma unroll
        for (int j = 0; j < 4; ++j)
            v[j] = ((const u16x8*)(xb + (size_t)(q[j].x & 0xFFFFF) * PROJ))[l32];
#pragma unroll
        for (int j = 0; j < 4; ++j) {
            float4 c = *(const float4*)(comp_l + ((q[j].x >> 20) & 31) * NB);
            float nn = __uint_as_float(q[j].y);
            a0 += nn * (c.x*bf2f(v[j][0]) + c.y*bf2f(v[j][1]) + c.z*bf2f(v[j][2]) + c.w*bf2f(v[j][3]));
            a1 += nn * (c.x*bf2f(v[j][4]) + c.y*bf2f(v[j][5]) + c.z*bf2f(v[j][6]) + c.w*bf2f(v[j][7]));
        }
        k += 4;
    }
    for (; k < deg; ++k) {
        uint2 q = r[k];
        u16x8 v = ((const u16x8*)(xb + (size_t)(q.x & 0xFFFFF) * PROJ))[l32];
        float4 c = *(const float4*)(comp_l + ((q.x >> 20) & 31) * NB);
        float nn = __uint_as_float(q.y);
        a0 += nn * (c.x*bf2f(v[0]) + c.y*bf2f(v[1]) + c.z*bf2f(v[2]) + c.w*bf2f(v[3]));
        a1 += nn * (c.x*bf2f(v[4]) + c.y*bf2f(v[5]) + c.z*bf2f(v[6]) + c.w*bf2f(v[7]));
    }
    int o = 2 * l32;
    size_t ob = (size_t)d * HD + o;
    float r0 = fmaxf(a0 + bias_l[o],     0.f) + f[ob];
    float r1 = fmaxf(a1 + bias_l[o + 1], 0.f) + f[ob + 1];
    *(float2*)(out + ob) = make_float2(r0, r1);
}

extern "C" void kernel_launch(void* const* d_in, const int* in_sizes, int n_in,
                              void* d_out, int out_size, void* d_ws, size_t ws_size,
                              hipStream_t stream) {
    const float* features = (const float*)d_in[0];
    const float* norm     = (const float*)d_in[1];
    const float* V        = (const float*)d_in[2];
    const float* comp     = (const float*)d_in[3];
    const float* bias     = (const float*)d_in[4];
    const int*   src      = (const int*)d_in[5];
    const int*   dst      = (const int*)d_in[6];
    const int*   etype    = (const int*)d_in[7];
    float* out = (float*)d_out;

    int n_nodes = in_sizes[0] / HD;
    int n_edges = in_sizes[5];
    int L       = in_sizes[2] / (NB * HD * HD);   // N_HID
    int l       = L - 1;                          // only the last layer survives
    int comp_stride = in_sizes[3] / L;            // NUM_RELS * NB

    const float* Vl     = V    + (size_t)l * NB * HD * HD;
    const float* comp_l = comp + (size_t)l * comp_stride;
    const float* bias_l = bias + (size_t)l * HD;

    // workspace carve-up
    char* ws = (char*)d_ws;
    unsigned short* xb = (unsigned short*)ws;                 // bf16 [n_nodes, 256]
    size_t off = (size_t)n_nodes * PROJ * sizeof(unsigned short);
    int* cnt    = (int*)(ws + off);  off += (size_t)n_nodes * sizeof(int);
    int* offs   = (int*)(ws + off);  off += (size_t)n_nodes * sizeof(int);
    int* cursor = (int*)(ws + off);  off += (size_t)n_nodes * sizeof(int);
    int* bsum   = (int*)(ws + off);  off += 1024 * sizeof(int);
    unsigned short* wpack = (unsigned short*)(ws + off); off += 2048 * 8 * sizeof(unsigned short);
    off = (off + 7) & ~(size_t)7;
    uint2* rec  = (uint2*)(ws + off);                         // [n_edges]

    hipMemsetAsync(cnt, 0, (size_t)n_nodes * sizeof(int), stream);

    int eblocks = (n_edges + 255) / 256;
    int pblocks = (n_nodes + 63) / 64;

    // hist + wpack fused (independent)
    histpack_kernel<<<eblocks + 1, 256, 0, stream>>>(dst, cnt, n_edges, Vl, wpack, eblocks);

    int nblk = (n_nodes + SCAN_BLK - 1) / SCAN_BLK;           // <= 256
    scan_a_kernel<<<nblk, 256, 0, stream>>>(cnt, offs, bsum, n_nodes);
    scan_b_kernel<<<1, 256, 0, stream>>>(bsum, nblk);
    scan_c_kernel<<<(n_nodes + 255) / 256, 256, 0, stream>>>(offs, cursor, bsum, n_nodes);

    // scatter + proj fused (independent; both feed seg2)
    scatterproj_kernel<<<eblocks + pblocks, 256, 0, stream>>>(
        src, dst, etype, norm, cursor, rec, n_edges, eblocks,
        features, wpack, xb, n_nodes);

    seg2_kernel<<<(n_nodes + 7) / 8, 256, 0, stream>>>(
        rec, offs, xb, comp_l, bias_l, features, out, n_nodes, n_edges);
}

// Round 9
// 178.402 us; speedup vs baseline: 1.3223x; 1.3223x over previous
//
#include <hip/hip_runtime.h>

#define HD   64
#define NB   4
#define PROJ 256   // HD * NB columns
#define SCAN_BLK 1024

typedef __attribute__((ext_vector_type(8))) short bf16x8;
typedef __attribute__((ext_vector_type(4))) float f32x4;
typedef __attribute__((ext_vector_type(8))) unsigned short u16x8;

__device__ __forceinline__ float bf2f(unsigned short u) {
    union { unsigned int i; float f; } c; c.i = ((unsigned int)u) << 16; return c.f;
}
__device__ __forceinline__ unsigned short f2bf(float f) {
    union { float f; unsigned int i; } c; c.f = f;
    unsigned int r = c.i + 0x7FFF + ((c.i >> 16) & 1);   // round-to-nearest-even
    return (unsigned short)(r >> 16);
}

// ---- fused: blocks [0,eblocks) histogram + rank capture; block eblocks packs W ----
__global__ __launch_bounds__(256) void histpack_kernel(
    const int* __restrict__ dst, int* __restrict__ cnt, int* __restrict__ rank,
    int n_edges, const float* __restrict__ Vl, unsigned short* __restrict__ wpack,
    int eblocks) {
    if ((int)blockIdx.x == eblocks) {
        int t = threadIdx.x;
#pragma unroll
        for (int i = 0; i < 8; ++i) {
            int s = t + i * 256;            // 0..2047 lane-slots
            int lane = s & 63;
            int ksct = s >> 6;
            int ks = ksct & 1, ct = ksct >> 1;
            int c = ct * 16 + (lane & 15);
            int o = c >> 2, b = c & 3;
            unsigned int w[4];
#pragma unroll
            for (int j = 0; j < 4; ++j) {
                int k0 = ks * 32 + ((lane >> 4) & 3) * 8 + 2 * j;
                unsigned short lo = f2bf(Vl[((size_t)b * HD + k0) * HD + o]);
                unsigned short hi = f2bf(Vl[((size_t)b * HD + k0 + 1) * HD + o]);
                w[j] = (unsigned)lo | ((unsigned)hi << 16);
            }
            *(uint4*)(wpack + (size_t)s * 8) = make_uint4(w[0], w[1], w[2], w[3]);
        }
        return;
    }
    int e = blockIdx.x * 256 + threadIdx.x;
    if (e < n_edges) rank[e] = atomicAdd(&cnt[dst[e]], 1);  // rank = old count
}

// ---- scans ----
__global__ __launch_bounds__(256) void scan_a_kernel(
    const int* __restrict__ cnt, int* __restrict__ offs,
    int* __restrict__ bsum, int n) {
    __shared__ int sd[256];
    int t = threadIdx.x;
    int base = blockIdx.x * SCAN_BLK + t * 4;
    int v[4];
#pragma unroll
    for (int j = 0; j < 4; ++j) v[j] = (base + j < n) ? cnt[base + j] : 0;
    int s = v[0] + v[1] + v[2] + v[3];
    sd[t] = s; __syncthreads();
    for (int off = 1; off < 256; off <<= 1) {
        int x = (t >= off) ? sd[t - off] : 0;
        __syncthreads();
        sd[t] += x;
        __syncthreads();
    }
    int excl = sd[t] - s;
    if (t == 255) bsum[blockIdx.x] = sd[t];
    int run = excl;
#pragma unroll
    for (int j = 0; j < 4; ++j) {
        if (base + j < n) offs[base + j] = run;
        run += v[j];
    }
}

__global__ __launch_bounds__(256) void scan_b_kernel(int* __restrict__ bsum, int nblk) {
    __shared__ int sd[256];
    int t = threadIdx.x;
    int s = (t < nblk) ? bsum[t] : 0;
    sd[t] = s; __syncthreads();
    for (int off = 1; off < 256; off <<= 1) {
        int x = (t >= off) ? sd[t - off] : 0;
        __syncthreads();
        sd[t] += x;
        __syncthreads();
    }
    if (t < nblk) bsum[t] = sd[t] - s;
}

__global__ __launch_bounds__(256) void scan_c_kernel(
    int* __restrict__ offs, const int* __restrict__ bsum, int n) {
    int i = blockIdx.x * 256 + threadIdx.x;
    if (i < n) offs[i] += bsum[i / SCAN_BLK];
}

// ---- fused scatter (atomic-free) + MFMA proj, evenly interleaved roles ----
#define FS_STRIDE 72
__global__ __launch_bounds__(256, 4) void scatterproj_kernel(
    // scatter args
    const int* __restrict__ src, const int* __restrict__ dst,
    const int* __restrict__ etype, const float* __restrict__ norm,
    const int* __restrict__ offs, const int* __restrict__ rank,
    uint2* __restrict__ rec, int n_edges, int eblocks, int pblocks,
    // proj args
    const float* __restrict__ f, const unsigned short* __restrict__ wpack,
    unsigned short* __restrict__ xb, int n_nodes) {
    __shared__ unsigned short fs[64 * FS_STRIDE];
    long long tot = eblocks + pblocks;
    long long i = blockIdx.x;
    int pj_before = (int)((i * pblocks) / tot);
    int pj_after  = (int)(((i + 1) * pblocks) / tot);
    if (pj_after == pj_before) {
        // scatter role
        int sid = (int)i - pj_before;
        int e = sid * 256 + threadIdx.x;
        if (e >= n_edges) return;
        int d = dst[e];
        uint2 rr;
        rr.x = (unsigned)src[e] | ((unsigned)etype[e] << 20);
        rr.y = __float_as_uint(norm[e]);
        rec[offs[d] + rank[e]] = rr;       // unique slot, no atomic
        return;
    }
    // proj role
    int bid = pj_before;
    int t = threadIdx.x;
    int lane = t & 63;
    int wt = t >> 6;
    int n0 = bid * 64;

#pragma unroll
    for (int ii = 0; ii < 4; ++ii) {
        int idx = t + ii * 256;
        int node = idx >> 4;
        int kg = idx & 15;
        unsigned int lo = 0, hi = 0;
        if (n0 + node < n_nodes) {
            float4 v = *(const float4*)(f + ((size_t)(n0 + node) * HD + kg * 4));
            lo = (unsigned)f2bf(v.x) | ((unsigned)f2bf(v.y) << 16);
            hi = (unsigned)f2bf(v.z) | ((unsigned)f2bf(v.w) << 16);
        }
        *(uint2*)(fs + node * FS_STRIDE + kg * 4) = make_uint2(lo, hi);
    }
    __syncthreads();

    bf16x8 bfr[2];
#pragma unroll
    for (int ks = 0; ks < 2; ++ks) {
        int off = (wt * 16 + (lane & 15)) * FS_STRIDE + ks * 32 + ((lane >> 4) & 3) * 8;
        bfr[ks] = *reinterpret_cast<const bf16x8*>(&fs[off]);
    }

    f32x4 acc[16];
#pragma unroll
    for (int ct = 0; ct < 16; ++ct) acc[ct] = (f32x4){0.f, 0.f, 0.f, 0.f};

#pragma unroll
    for (int ct = 0; ct < 16; ++ct) {
#pragma unroll
        for (int ks = 0; ks < 2; ++ks) {
            bf16x8 a = *reinterpret_cast<const bf16x8*>(
                wpack + ((size_t)(ct * 2 + ks) * 64 + lane) * 8);
            acc[ct] = __builtin_amdgcn_mfma_f32_16x16x32_bf16(a, bfr[ks], acc[ct], 0, 0, 0);
        }
    }

    int node = n0 + wt * 16 + (lane & 15);
    if (node < n_nodes) {
#pragma unroll
        for (int ct = 0; ct < 16; ++ct) {
            int c0 = ct * 16 + ((lane >> 4) & 3) * 4;
            unsigned int lo = (unsigned)f2bf(acc[ct][0]) | ((unsigned)f2bf(acc[ct][1]) << 16);
            unsigned int hi = (unsigned)f2bf(acc[ct][2]) | ((unsigned)f2bf(acc[ct][3]) << 16);
            *(uint2*)(xb + (size_t)node * PROJ + c0) = make_uint2(lo, hi);
        }
    }
}

// ---- segmented sum: one dst per 32-lane half-wave, 8-deep ILP ----
__global__ __launch_bounds__(256) void seg2_kernel(
    const uint2* __restrict__ rec, const int* __restrict__ offs,
    const unsigned short* __restrict__ xb,
    const float* __restrict__ comp_l, const float* __restrict__ bias_l,
    const float* __restrict__ f, float* __restrict__ out,
    int n_nodes, int n_edges) {
    int d = blockIdx.x * 8 + (threadIdx.x >> 5);
    if (d >= n_nodes) return;
    int l32 = threadIdx.x & 31;
    int start = offs[d];
    int end = (d + 1 < n_nodes) ? offs[d + 1] : n_edges;
    int deg = end - start;
    const uint2* r = rec + start;
    float a0 = 0.f, a1 = 0.f;
    int k = 0;
    for (; k + 7 < deg; k += 8) {
        uint2 q[8]; u16x8 v[8];
#pragma unroll
        for (int j = 0; j < 8; ++j) q[j] = r[k + j];
#pragma unroll
        for (int j = 0; j < 8; ++j)
            v[j] = ((const u16x8*)(xb + (size_t)(q[j].x & 0xFFFFF) * PROJ))[l32];
#pragma unroll
        for (int j = 0; j < 8; ++j) {
            float4 c = *(const float4*)(comp_l + ((q[j].x >> 20) & 31) * NB);
            float nn = __uint_as_float(q[j].y);
            a0 += nn * (c.x*bf2f(v[j][0]) + c.y*bf2f(v[j][1]) + c.z*bf2f(v[j][2]) + c.w*bf2f(v[j][3]));
            a1 += nn * (c.x*bf2f(v[j][4]) + c.y*bf2f(v[j][5]) + c.z*bf2f(v[j][6]) + c.w*bf2f(v[j][7]));
        }
    }
    if (k + 3 < deg) {
        uint2 q[4]; u16x8 v[4];
#pragma unroll
        for (int j = 0; j < 4; ++j) q[j] = r[k + j];
#pragma unroll
        for (int j = 0; j < 4; ++j)
            v[j] = ((const u16x8*)(xb + (size_t)(q[j].x & 0xFFFFF) * PROJ))[l32];
#pragma unroll
        for (int j = 0; j < 4; ++j) {
            float4 c = *(const float4*)(comp_l + ((q[j].x >> 20) & 31) * NB);
            float nn = __uint_as_float(q[j].y);
            a0 += nn * (c.x*bf2f(v[j][0]) + c.y*bf2f(v[j][1]) + c.z*bf2f(v[j][2]) + c.w*bf2f(v[j][3]));
            a1 += nn * (c.x*bf2f(v[j][4]) + c.y*bf2f(v[j][5]) + c.z*bf2f(v[j][6]) + c.w*bf2f(v[j][7]));
        }
        k += 4;
    }
    for (; k < deg; ++k) {
        uint2 q = r[k];
        u16x8 v = ((const u16x8*)(xb + (size_t)(q.x & 0xFFFFF) * PROJ))[l32];
        float4 c = *(const float4*)(comp_l + ((q.x >> 20) & 31) * NB);
        float nn = __uint_as_float(q.y);
        a0 += nn * (c.x*bf2f(v[0]) + c.y*bf2f(v[1]) + c.z*bf2f(v[2]) + c.w*bf2f(v[3]));
        a1 += nn * (c.x*bf2f(v[4]) + c.y*bf2f(v[5]) + c.z*bf2f(v[6]) + c.w*bf2f(v[7]));
    }
    int o = 2 * l32;
    size_t ob = (size_t)d * HD + o;
    float r0 = fmaxf(a0 + bias_l[o],     0.f) + f[ob];
    float r1 = fmaxf(a1 + bias_l[o + 1], 0.f) + f[ob + 1];
    *(float2*)(out + ob) = make_float2(r0, r1);
}

extern "C" void kernel_launch(void* const* d_in, const int* in_sizes, int n_in,
                              void* d_out, int out_size, void* d_ws, size_t ws_size,
                              hipStream_t stream) {
    const float* features = (const float*)d_in[0];
    const float* norm     = (const float*)d_in[1];
    const float* V        = (const float*)d_in[2];
    const float* comp     = (const float*)d_in[3];
    const float* bias     = (const float*)d_in[4];
    const int*   src      = (const int*)d_in[5];
    const int*   dst      = (const int*)d_in[6];
    const int*   etype    = (const int*)d_in[7];
    float* out = (float*)d_out;

    int n_nodes = in_sizes[0] / HD;
    int n_edges = in_sizes[5];
    int L       = in_sizes[2] / (NB * HD * HD);   // N_HID
    int l       = L - 1;                          // only the last layer survives
    int comp_stride = in_sizes[3] / L;            // NUM_RELS * NB

    const float* Vl     = V    + (size_t)l * NB * HD * HD;
    const float* comp_l = comp + (size_t)l * comp_stride;
    const float* bias_l = bias + (size_t)l * HD;

    // workspace carve-up
    char* ws = (char*)d_ws;
    unsigned short* xb = (unsigned short*)ws;                 // bf16 [n_nodes, 256]
    size_t off = (size_t)n_nodes * PROJ * sizeof(unsigned short);
    int* cnt    = (int*)(ws + off);  off += (size_t)n_nodes * sizeof(int);
    int* offs   = (int*)(ws + off);  off += (size_t)n_nodes * sizeof(int);
    int* rank   = (int*)(ws + off);  off += (size_t)n_edges * sizeof(int);
    int* bsum   = (int*)(ws + off);  off += 1024 * sizeof(int);
    unsigned short* wpack = (unsigned short*)(ws + off); off += 2048 * 8 * sizeof(unsigned short);
    off = (off + 7) & ~(size_t)7;
    uint2* rec  = (uint2*)(ws + off);                         // [n_edges]

    hipMemsetAsync(cnt, 0, (size_t)n_nodes * sizeof(int), stream);

    int eblocks = (n_edges + 255) / 256;
    int pblocks = (n_nodes + 63) / 64;

    // hist (+rank capture) + wpack fused
    histpack_kernel<<<eblocks + 1, 256, 0, stream>>>(dst, cnt, rank, n_edges,
                                                     Vl, wpack, eblocks);

    int nblk = (n_nodes + SCAN_BLK - 1) / SCAN_BLK;           // <= 256
    scan_a_kernel<<<nblk, 256, 0, stream>>>(cnt, offs, bsum, n_nodes);
    scan_b_kernel<<<1, 256, 0, stream>>>(bsum, nblk);
    scan_c_kernel<<<(n_nodes + 255) / 256, 256, 0, stream>>>(offs, bsum, n_nodes);

    // atomic-free scatter + proj, roles evenly interleaved across the grid
    scatterproj_kernel<<<eblocks + pblocks, 256, 0, stream>>>(
        src, dst, etype, norm, offs, rank, rec, n_edges, eblocks, pblocks,
        features, wpack, xb, n_nodes);

    seg2_kernel<<<(n_nodes + 7) / 8, 256, 0, stream>>>(
        rec, offs, xb, comp_l, bias_l, features, out, n_nodes, n_edges);
}

// Round 10
// 123.997 us; speedup vs baseline: 1.9024x; 1.4388x over previous
//
#include <hip/hip_runtime.h>

#define HD   64
#define NB   4
#define SCAN_BLK 1024

typedef __attribute__((ext_vector_type(8))) short bf16x8;
typedef __attribute__((ext_vector_type(4))) float f32x4;

__device__ __forceinline__ float bf2f(unsigned short u) {
    union { unsigned int i; float f; } c; c.i = ((unsigned int)u) << 16; return c.f;
}
__device__ __forceinline__ unsigned short f2bf(float f) {
    union { float f; unsigned int i; } c; c.f = f;
    unsigned int r = c.i + 0x7FFF + ((c.i >> 16) & 1);   // round-to-nearest-even
    return (unsigned short)(r >> 16);
}
__device__ __forceinline__ unsigned int pack2(float a, float b) {
    return (unsigned)f2bf(a) | ((unsigned)f2bf(b) << 16);
}

// ---- fused: blocks [0,eblocks) histogram + rank; block eblocks packs V fragments ----
// vpack[((ct*8+ks)*64 + lane)*8 + m] = W2[ks*32 + ((lane>>4)&3)*8 + m][ct*16 + (lane&15)]
// W2[k][o] = Vl[k*64 + o]   (k = b*64 + i, exactly Vl's layout flattened)
__global__ __launch_bounds__(256) void histpack_kernel(
    const int* __restrict__ dst, int* __restrict__ cnt, int* __restrict__ rank,
    int n_edges, const float* __restrict__ Vl, unsigned short* __restrict__ vpack,
    int eblocks) {
    if ((int)blockIdx.x == eblocks) {
        int t = threadIdx.x;
#pragma unroll
        for (int i = 0; i < 8; ++i) {
            int s = t + i * 256;            // 0..2047 lane-slots
            int lane = s & 63;
            int ctks = s >> 6;              // 0..31
            int ks = ctks & 7, ct = ctks >> 3;
            int o = ct * 16 + (lane & 15);
            unsigned int w[4];
#pragma unroll
            for (int j = 0; j < 4; ++j) {
                int k0 = ks * 32 + ((lane >> 4) & 3) * 8 + 2 * j;
                w[j] = pack2(Vl[(size_t)k0 * HD + o], Vl[(size_t)(k0 + 1) * HD + o]);
            }
            *(uint4*)(vpack + (size_t)s * 8) = make_uint4(w[0], w[1], w[2], w[3]);
        }
        return;
    }
    int e = blockIdx.x * 256 + threadIdx.x;
    if (e < n_edges) rank[e] = atomicAdd(&cnt[dst[e]], 1);
}

// ---- scans ----
__global__ __launch_bounds__(256) void scan_a_kernel(
    const int* __restrict__ cnt, int* __restrict__ offs,
    int* __restrict__ bsum, int n) {
    __shared__ int sd[256];
    int t = threadIdx.x;
    int base = blockIdx.x * SCAN_BLK + t * 4;
    int v[4];
#pragma unroll
    for (int j = 0; j < 4; ++j) v[j] = (base + j < n) ? cnt[base + j] : 0;
    int s = v[0] + v[1] + v[2] + v[3];
    sd[t] = s; __syncthreads();
    for (int off = 1; off < 256; off <<= 1) {
        int x = (t >= off) ? sd[t - off] : 0;
        __syncthreads();
        sd[t] += x;
        __syncthreads();
    }
    int excl = sd[t] - s;
    if (t == 255) bsum[blockIdx.x] = sd[t];
    int run = excl;
#pragma unroll
    for (int j = 0; j < 4; ++j) {
        if (base + j < n) offs[base + j] = run;
        run += v[j];
    }
}

__global__ __launch_bounds__(256) void scan_b_kernel(int* __restrict__ bsum, int nblk) {
    __shared__ int sd[256];
    int t = threadIdx.x;
    int s = (t < nblk) ? bsum[t] : 0;
    sd[t] = s; __syncthreads();
    for (int off = 1; off < 256; off <<= 1) {
        int x = (t >= off) ? sd[t - off] : 0;
        __syncthreads();
        sd[t] += x;
        __syncthreads();
    }
    if (t < nblk) bsum[t] = sd[t] - s;
}

__global__ __launch_bounds__(256) void scan_c_kernel(
    int* __restrict__ offs, const int* __restrict__ bsum, int n) {
    int i = blockIdx.x * 256 + threadIdx.x;
    if (i < n) offs[i] += bsum[i / SCAN_BLK];
}

// ---- fused: atomic-free scatter + feature bf16 conversion, interleaved roles ----
__global__ __launch_bounds__(256) void scatterfb_kernel(
    const int* __restrict__ src, const int* __restrict__ dst,
    const int* __restrict__ etype, const float* __restrict__ norm,
    const int* __restrict__ offs, const int* __restrict__ rank,
    uint2* __restrict__ rec, int n_edges, int eblocks, int fbblocks,
    const float* __restrict__ f, unsigned short* __restrict__ fb, int n_nodes) {
    long long tot = eblocks + fbblocks;
    long long i = blockIdx.x;
    int fb_before = (int)((i * fbblocks) / tot);
    int fb_after  = (int)(((i + 1) * fbblocks) / tot);
    if (fb_after == fb_before) {
        // scatter role
        int sid = (int)i - fb_before;
        int e = sid * 256 + threadIdx.x;
        if (e >= n_edges) return;
        int d = dst[e];
        uint2 rr;
        rr.x = (unsigned)src[e] | ((unsigned)etype[e] << 20);
        rr.y = __float_as_uint(norm[e]);
        rec[offs[d] + rank[e]] = rr;       // unique slot, no atomic
        return;
    }
    // fb-convert role: 8 f32 -> 8 bf16 per thread
    int gid = fb_before * 256 + threadIdx.x;
    long long base = (long long)gid * 8;
    long long total = (long long)n_nodes * HD;
    if (base + 7 < total) {
        float4 v0 = *(const float4*)(f + base);
        float4 v1 = *(const float4*)(f + base + 4);
        uint4 p = make_uint4(pack2(v0.x, v0.y), pack2(v0.z, v0.w),
                             pack2(v1.x, v1.y), pack2(v1.z, v1.w));
        ((uint4*)fb)[gid] = p;
    }
}

// ---- aggregate-then-project: 16 dsts/block, half-wave per dst, MFMA epilogue ----
// g layout in LDS (as 2xbf16 dwords): glds[n*132 + b*32 + l32]  (row stride 528B)
#define G_STRIDE_U32 132
__global__ __launch_bounds__(256) void aggproj_kernel(
    const uint2* __restrict__ rec, const int* __restrict__ offs,
    const unsigned int* __restrict__ fb32,   // fb as uint (2 bf16)
    const float* __restrict__ comp_l, const float* __restrict__ bias_l,
    const float* __restrict__ f, float* __restrict__ out,
    const unsigned short* __restrict__ vpack, int n_nodes, int n_edges) {
    __shared__ unsigned int glds[16 * G_STRIDE_U32];
    int t = threadIdx.x;
    int l32 = t & 31;
    int halfbase = t & 32;                   // shfl base lane of this half-wave
    int hw = t >> 5;                         // half-wave id 0..7
    int wv = t >> 6;                         // wave id 0..3
    int d0 = blockIdx.x * 16;
    const float4* comp4 = (const float4*)comp_l;

#pragma unroll
    for (int ss = 0; ss < 2; ++ss) {
        int n = hw + ss * 8;                 // local dst 0..15
        int d = d0 + n;
        float a00 = 0.f, a01 = 0.f, a10 = 0.f, a11 = 0.f;
        float a20 = 0.f, a21 = 0.f, a30 = 0.f, a31 = 0.f;
        if (d < n_nodes) {
            int start = offs[d];
            int end = (d + 1 < n_nodes) ? offs[d + 1] : n_edges;
            int deg = end - start;
            for (int cb = 0; cb < deg; cb += 32) {
                int m = deg - cb; if (m > 32) m = 32;
                uint2 myq = make_uint2(0u, 0u);
                if (cb + l32 < deg) myq = rec[start + cb + l32];   // coalesced
                int j = 0;
                for (; j + 3 < m; j += 4) {
                    unsigned qx0 = __shfl(myq.x, halfbase + j,     64);
                    unsigned qy0 = __shfl(myq.y, halfbase + j,     64);
                    unsigned qx1 = __shfl(myq.x, halfbase + j + 1, 64);
                    unsigned qy1 = __shfl(myq.y, halfbase + j + 1, 64);
                    unsigned qx2 = __shfl(myq.x, halfbase + j + 2, 64);
                    unsigned qy2 = __shfl(myq.y, halfbase + j + 2, 64);
                    unsigned qx3 = __shfl(myq.x, halfbase + j + 3, 64);
                    unsigned qy3 = __shfl(myq.y, halfbase + j + 3, 64);
                    unsigned fw0 = fb32[(size_t)(qx0 & 0xFFFFF) * 32 + l32];
                    unsigned fw1 = fb32[(size_t)(qx1 & 0xFFFFF) * 32 + l32];
                    unsigned fw2 = fb32[(size_t)(qx2 & 0xFFFFF) * 32 + l32];
                    unsigned fw3 = fb32[(size_t)(qx3 & 0xFFFFF) * 32 + l32];
                    float4 c0 = comp4[(qx0 >> 20) & 31];
                    float4 c1 = comp4[(qx1 >> 20) & 31];
                    float4 c2 = comp4[(qx2 >> 20) & 31];
                    float4 c3 = comp4[(qx3 >> 20) & 31];
                    float nn0 = __uint_as_float(qy0), nn1 = __uint_as_float(qy1);
                    float nn2 = __uint_as_float(qy2), nn3 = __uint_as_float(qy3);
                    {
                        float f0 = bf2f((unsigned short)(fw0 & 0xFFFF));
                        float f1 = bf2f((unsigned short)(fw0 >> 16));
                        float w0 = nn0 * c0.x, w1 = nn0 * c0.y, w2 = nn0 * c0.z, w3 = nn0 * c0.w;
                        a00 += w0 * f0; a01 += w0 * f1; a10 += w1 * f0; a11 += w1 * f1;
                        a20 += w2 * f0; a21 += w2 * f1; a30 += w3 * f0; a31 += w3 * f1;
                    }
                    {
                        float f0 = bf2f((unsigned short)(fw1 & 0xFFFF));
                        float f1 = bf2f((unsigned short)(fw1 >> 16));
                        float w0 = nn1 * c1.x, w1 = nn1 * c1.y, w2 = nn1 * c1.z, w3 = nn1 * c1.w;
                        a00 += w0 * f0; a01 += w0 * f1; a10 += w1 * f0; a11 += w1 * f1;
                        a20 += w2 * f0; a21 += w2 * f1; a30 += w3 * f0; a31 += w3 * f1;
                    }
                    {
                        float f0 = bf2f((unsigned short)(fw2 & 0xFFFF));
                        float f1 = bf2f((unsigned short)(fw2 >> 16));
                        float w0 = nn2 * c2.x, w1 = nn2 * c2.y, w2 = nn2 * c2.z, w3 = nn2 * c2.w;
                        a00 += w0 * f0; a01 += w0 * f1; a10 += w1 * f0; a11 += w1 * f1;
                        a20 += w2 * f0; a21 += w2 * f1; a30 += w3 * f0; a31 += w3 * f1;
                    }
                    {
                        float f0 = bf2f((unsigned short)(fw3 & 0xFFFF));
                        float f1 = bf2f((unsigned short)(fw3 >> 16));
                        float w0 = nn3 * c3.x, w1 = nn3 * c3.y, w2 = nn3 * c3.z, w3 = nn3 * c3.w;
                        a00 += w0 * f0; a01 += w0 * f1; a10 += w1 * f0; a11 += w1 * f1;
                        a20 += w2 * f0; a21 += w2 * f1; a30 += w3 * f0; a31 += w3 * f1;
                    }
                }
                for (; j < m; ++j) {
                    unsigned qx = __shfl(myq.x, halfbase + j, 64);
                    unsigned qy = __shfl(myq.y, halfbase + j, 64);
                    unsigned fw = fb32[(size_t)(qx & 0xFFFFF) * 32 + l32];
                    float4 c = comp4[(qx >> 20) & 31];
                    float nn = __uint_as_float(qy);
                    float f0 = bf2f((unsigned short)(fw & 0xFFFF));
                    float f1 = bf2f((unsigned short)(fw >> 16));
                    float w0 = nn * c.x, w1 = nn * c.y, w2 = nn * c.z, w3 = nn * c.w;
                    a00 += w0 * f0; a01 += w0 * f1; a10 += w1 * f0; a11 += w1 * f1;
                    a20 += w2 * f0; a21 += w2 * f1; a30 += w3 * f0; a31 += w3 * f1;
                }
            }
        }
        // write g as 2xbf16 dwords: k = b*64 + 2*l32 (+1)
        glds[n * G_STRIDE_U32 + 0 * 32 + l32] = pack2(a00, a01);
        glds[n * G_STRIDE_U32 + 1 * 32 + l32] = pack2(a10, a11);
        glds[n * G_STRIDE_U32 + 2 * 32 + l32] = pack2(a20, a21);
        glds[n * G_STRIDE_U32 + 3 * 32 + l32] = pack2(a30, a31);
    }
    __syncthreads();

    // MFMA projection: wave wv owns output tile ct = wv (o = ct*16..+16), K = 256
    int lane = t & 63;
    int row = lane & 15;                     // dst within block
    int hi = (lane >> 4) & 3;
    int ct = wv;
    f32x4 acc = (f32x4){0.f, 0.f, 0.f, 0.f};
#pragma unroll
    for (int ks = 0; ks < 8; ++ks) {
        bf16x8 bfrag = *reinterpret_cast<const bf16x8*>(
            (const char*)glds + row * (G_STRIDE_U32 * 4) + ks * 64 + hi * 16);
        bf16x8 afrag = *reinterpret_cast<const bf16x8*>(
            vpack + ((size_t)(ct * 8 + ks) * 64 + lane) * 8);
        acc = __builtin_amdgcn_mfma_f32_16x16x32_bf16(afrag, bfrag, acc, 0, 0, 0);
    }
    int dst_n = d0 + row;
    if (dst_n < n_nodes) {
        int o0 = ct * 16 + hi * 4;
        float4 b4 = *(const float4*)(bias_l + o0);
        float4 fv = *(const float4*)(f + (size_t)dst_n * HD + o0);
        float4 res;
        res.x = fmaxf(acc[0] + b4.x, 0.f) + fv.x;
        res.y = fmaxf(acc[1] + b4.y, 0.f) + fv.y;
        res.z = fmaxf(acc[2] + b4.z, 0.f) + fv.z;
        res.w = fmaxf(acc[3] + b4.w, 0.f) + fv.w;
        *(float4*)(out + (size_t)dst_n * HD + o0) = res;
    }
}

extern "C" void kernel_launch(void* const* d_in, const int* in_sizes, int n_in,
                              void* d_out, int out_size, void* d_ws, size_t ws_size,
                              hipStream_t stream) {
    const float* features = (const float*)d_in[0];
    const float* norm     = (const float*)d_in[1];
    const float* V        = (const float*)d_in[2];
    const float* comp     = (const float*)d_in[3];
    const float* bias     = (const float*)d_in[4];
    const int*   src      = (const int*)d_in[5];
    const int*   dst      = (const int*)d_in[6];
    const int*   etype    = (const int*)d_in[7];
    float* out = (float*)d_out;

    int n_nodes = in_sizes[0] / HD;
    int n_edges = in_sizes[5];
    int L       = in_sizes[2] / (NB * HD * HD);   // N_HID
    int l       = L - 1;                          // only the last layer survives
    int comp_stride = in_sizes[3] / L;            // NUM_RELS * NB

    const float* Vl     = V    + (size_t)l * NB * HD * HD;
    const float* comp_l = comp + (size_t)l * comp_stride;
    const float* bias_l = bias + (size_t)l * HD;

    // workspace carve-up
    char* ws = (char*)d_ws;
    size_t off = 0;
    unsigned short* fb = (unsigned short*)(ws + off); off += (size_t)n_nodes * HD * sizeof(unsigned short);
    off = (off + 15) & ~(size_t)15;
    int* cnt    = (int*)(ws + off);  off += (size_t)n_nodes * sizeof(int);
    int* offs   = (int*)(ws + off);  off += (size_t)n_nodes * sizeof(int);
    int* rank   = (int*)(ws + off);  off += (size_t)n_edges * sizeof(int);
    int* bsum   = (int*)(ws + off);  off += 1024 * sizeof(int);
    unsigned short* vpack = (unsigned short*)(ws + off); off += 2048 * 8 * sizeof(unsigned short);
    off = (off + 15) & ~(size_t)15;
    uint2* rec  = (uint2*)(ws + off);                         // [n_edges]

    hipMemsetAsync(cnt, 0, (size_t)n_nodes * sizeof(int), stream);

    int eblocks  = (n_edges + 255) / 256;
    long long total_el = (long long)n_nodes * HD;
    int fbblocks = (int)((total_el + 2047) / 2048);           // 8 elems/thread

    histpack_kernel<<<eblocks + 1, 256, 0, stream>>>(dst, cnt, rank, n_edges,
                                                     Vl, vpack, eblocks);

    int nblk = (n_nodes + SCAN_BLK - 1) / SCAN_BLK;           // <= 256
    scan_a_kernel<<<nblk, 256, 0, stream>>>(cnt, offs, bsum, n_nodes);
    scan_b_kernel<<<1, 256, 0, stream>>>(bsum, nblk);
    scan_c_kernel<<<(n_nodes + 255) / 256, 256, 0, stream>>>(offs, bsum, n_nodes);

    scatterfb_kernel<<<eblocks + fbblocks, 256, 0, stream>>>(
        src, dst, etype, norm, offs, rank, rec, n_edges, eblocks, fbblocks,
        features, fb, n_nodes);

    aggproj_kernel<<<(n_nodes + 15) / 16, 256, 0, stream>>>(
        rec, offs, (const unsigned int*)fb, comp_l, bias_l, features, out,
        vpack, n_nodes, n_edges);
}